// Round 1
// baseline (528.225 us; speedup 1.0000x reference)
//
#include <hip/hip_runtime.h>
#include <math.h>

// Problem constants: B=4, N=4096, D_in=256, D_out=128
#define NTOK 4096
#define RTOT 16384   // B*N
#define DIN  256
#define DOUT 128

constexpr float LEAKY = 0.01f;
constexpr float CEPS  = 0.001f;
constexpr float THR   = 0.1f;

// ---------------------------------------------------------------------------
// Kernel 1: H = leaky_relu(A @ W);  norms[r] = ||H[r,:]||_2
// A: [16384,256], W: [256,128], H: [16384,128], norms: [16384]
// grid 512 blocks x 256 threads; each block does 32 rows.
// Thread (tx=tid&31, ty=tid>>5): cols 4tx..4tx+3, rows ty+8i (i=0..3).
// ---------------------------------------------------------------------------
__global__ __launch_bounds__(256, 2) void proj_kernel(
    const float* __restrict__ A, const float* __restrict__ W,
    float* __restrict__ H, float* __restrict__ norms)
{
    __shared__ float As[32 * 256];   // 32 KB, row-major A tile
    const int tid  = threadIdx.x;
    const int row0 = blockIdx.x * 32;

    // Stage A tile: 32x256 floats = 2048 float4, contiguous (conflict-free)
    {
        const float4* src = (const float4*)(A + (size_t)row0 * DIN);
        float4* dst = (float4*)As;
        #pragma unroll
        for (int it = 0; it < 8; ++it)
            dst[tid + it * 256] = src[tid + it * 256];
    }
    __syncthreads();

    const int tx = tid & 31;    // col group: cols 4tx..4tx+3
    const int ty = tid >> 5;    // 0..7; rows ty + 8i

    float acc[4][4];
    #pragma unroll
    for (int i = 0; i < 4; ++i)
        #pragma unroll
        for (int j = 0; j < 4; ++j) acc[i][j] = 0.f;

    for (int k = 0; k < DIN; k += 4) {
        float4 w4[4];
        #pragma unroll
        for (int s = 0; s < 4; ++s)
            w4[s] = *(const float4*)(W + (size_t)(k + s) * DOUT + 4 * tx);
        #pragma unroll
        for (int i = 0; i < 4; ++i) {
            float4 a4 = *(const float4*)(As + (ty + 8 * i) * DIN + k);
            float ak[4] = {a4.x, a4.y, a4.z, a4.w};
            #pragma unroll
            for (int s = 0; s < 4; ++s) {
                float wj[4] = {w4[s].x, w4[s].y, w4[s].z, w4[s].w};
                #pragma unroll
                for (int j = 0; j < 4; ++j)
                    acc[i][j] = fmaf(ak[s], wj[j], acc[i][j]);
            }
        }
    }

    // leaky_relu, store H, reduce row norms across the 32 tx lanes
    #pragma unroll
    for (int i = 0; i < 4; ++i) {
        float h[4];
        float s = 0.f;
        #pragma unroll
        for (int j = 0; j < 4; ++j) {
            float v = acc[i][j];
            h[j] = (v >= 0.f) ? v : LEAKY * v;
            s = fmaf(h[j], h[j], s);
        }
        float4 hv = {h[0], h[1], h[2], h[3]};
        const int r = row0 + ty + 8 * i;
        *(float4*)(H + (size_t)r * DOUT + 4 * tx) = hv;
        // reduce over tx (lane bits 0..4 within the wave; ty bit untouched)
        #pragma unroll
        for (int m = 16; m >= 1; m >>= 1)
            s += __shfl_xor(s, m, 64);
        if (tx == 0) norms[r] = sqrtf(s);
    }
}

// ---------------------------------------------------------------------------
// Kernel 2: per batch b, out[i,j] = thresh(|dot(H_i,H_j) / max(n_i*n_j, eps)|)
// 64x64 output tile per block, K=128 fully resident in LDS.
// Thread (tx=tid&15, ty=tid>>4): rows ty+16i, cols tx+16j (i,j=0..3).
// LDS rows padded 128->132 floats: A-frag reads hit banks {0,4,8,12}
// (conflict-free), B-frag reads are 2-way (free), staging writes contiguous.
// ---------------------------------------------------------------------------
#define LDK 132
__global__ __launch_bounds__(256, 2) void cos_kernel(
    const float* __restrict__ H, const float* __restrict__ norms,
    float* __restrict__ out)
{
    __shared__ float As[64 * LDK];
    __shared__ float Bs[64 * LDK];

    const int b   = blockIdx.z;
    const int ti  = blockIdx.y * 64;
    const int tj  = blockIdx.x * 64;
    const int tid = threadIdx.x;
    const float* Hb = H + (size_t)b * NTOK * DOUT;

    // Stage both 64x128 tiles (2048 float4 each; 8 per thread per tile)
    #pragma unroll
    for (int it = 0; it < 8; ++it) {
        int idx = tid + it * 256;
        int r   = idx >> 5;
        int k4  = (idx & 31) << 2;
        *(float4*)(As + r * LDK + k4) =
            *(const float4*)(Hb + (size_t)(ti + r) * DOUT + k4);
        *(float4*)(Bs + r * LDK + k4) =
            *(const float4*)(Hb + (size_t)(tj + r) * DOUT + k4);
    }
    __syncthreads();

    const int tx = tid & 15;
    const int ty = tid >> 4;

    float acc[4][4];
    #pragma unroll
    for (int i = 0; i < 4; ++i)
        #pragma unroll
        for (int j = 0; j < 4; ++j) acc[i][j] = 0.f;

    for (int k = 0; k < DOUT; k += 4) {
        float4 a4[4], b4[4];
        #pragma unroll
        for (int i = 0; i < 4; ++i)
            a4[i] = *(const float4*)(As + (ty + 16 * i) * LDK + k);
        #pragma unroll
        for (int j = 0; j < 4; ++j)
            b4[j] = *(const float4*)(Bs + (tx + 16 * j) * LDK + k);
        #pragma unroll
        for (int i = 0; i < 4; ++i) {
            #pragma unroll
            for (int j = 0; j < 4; ++j) {
                acc[i][j] = fmaf(a4[i].x, b4[j].x, acc[i][j]);
                acc[i][j] = fmaf(a4[i].y, b4[j].y, acc[i][j]);
                acc[i][j] = fmaf(a4[i].z, b4[j].z, acc[i][j]);
                acc[i][j] = fmaf(a4[i].w, b4[j].w, acc[i][j]);
            }
        }
    }

    // Epilogue: cosine, abs, threshold
    float rn[4], cn[4];
    #pragma unroll
    for (int i = 0; i < 4; ++i) rn[i] = norms[b * NTOK + ti + ty + 16 * i];
    #pragma unroll
    for (int j = 0; j < 4; ++j) cn[j] = norms[b * NTOK + tj + tx + 16 * j];

    float* Ob = out + (size_t)b * NTOK * NTOK;
    #pragma unroll
    for (int i = 0; i < 4; ++i) {
        const size_t rowbase = (size_t)(ti + ty + 16 * i) * NTOK + tj;
        #pragma unroll
        for (int j = 0; j < 4; ++j) {
            float denom = fmaxf(rn[i] * cn[j], CEPS);
            float v = fabsf(acc[i][j] / denom);
            Ob[rowbase + tx + 16 * j] = (v > THR) ? v : 0.f;
        }
    }
}

extern "C" void kernel_launch(void* const* d_in, const int* in_sizes, int n_in,
                              void* d_out, int out_size, void* d_ws, size_t ws_size,
                              hipStream_t stream) {
    const float* A = (const float*)d_in[0];   // [4,4096,256]
    const float* W = (const float*)d_in[1];   // [256,128]
    float* out = (float*)d_out;               // [4,4096,4096]

    float* Hws   = (float*)d_ws;                       // 16384*128 floats = 8 MB
    float* norms = Hws + (size_t)RTOT * DOUT;          // 16384 floats

    proj_kernel<<<RTOT / 32, 256, 0, stream>>>(A, W, Hws, norms);
    cos_kernel<<<dim3(NTOK / 64, NTOK / 64, 4), 256, 0, stream>>>(Hws, norms, out);
}

// Round 2
// 420.594 us; speedup vs baseline: 1.2559x; 1.2559x over previous
//
#include <hip/hip_runtime.h>
#include <math.h>

// Problem constants: B=4, N=4096, D_in=256, D_out=128
#define NTOK 4096
#define RTOT 16384   // B*N
#define DIN  256
#define DOUT 128

constexpr float LEAKY = 0.01f;
constexpr float CEPS  = 0.001f;
constexpr float THR   = 0.1f;

// ---------------------------------------------------------------------------
// Kernel 1: H = leaky_relu(A @ W);  norms[r] = ||H[r,:]||_2
// 32 rows/block, 256 threads. W staged in LDS per 64-k chunk so inner-loop
// operand reads never touch global.
// Thread (tx=tid&31, ty=tid>>5): cols 4tx..4tx+3, rows ty+8i (i=0..3).
// ---------------------------------------------------------------------------
__global__ __launch_bounds__(256, 2) void proj_kernel(
    const float* __restrict__ A, const float* __restrict__ W,
    float* __restrict__ H, float* __restrict__ norms)
{
    __shared__ float As[32 * DIN];    // 32 KB
    __shared__ float Ws[64 * DOUT];   // 32 KB, one 64-row chunk of W
    const int tid  = threadIdx.x;
    const int row0 = blockIdx.x * 32;

    // Stage A tile: 32x256 floats = 2048 float4, contiguous
    {
        const float4* src = (const float4*)(A + (size_t)row0 * DIN);
        float4* dst = (float4*)As;
        #pragma unroll
        for (int it = 0; it < 8; ++it)
            dst[tid + it * 256] = src[tid + it * 256];
    }

    const int tx = tid & 31;    // col group: cols 4tx..4tx+3
    const int ty = tid >> 5;    // 0..7; rows ty + 8i

    float acc[4][4];
    #pragma unroll
    for (int i = 0; i < 4; ++i)
        #pragma unroll
        for (int j = 0; j < 4; ++j) acc[i][j] = 0.f;

    for (int kc = 0; kc < DIN; kc += 64) {
        __syncthreads();   // covers A staging (first iter) + Ws reuse (later)
        {
            const float4* wsrc = (const float4*)(W + (size_t)kc * DOUT);
            float4* wdst = (float4*)Ws;
            #pragma unroll
            for (int it = 0; it < 8; ++it)
                wdst[tid + it * 256] = wsrc[tid + it * 256];
        }
        __syncthreads();

        for (int k = 0; k < 64; k += 4) {
            float4 w4[4];
            #pragma unroll
            for (int s = 0; s < 4; ++s)
                w4[s] = *(const float4*)(Ws + (k + s) * DOUT + 4 * tx);
            #pragma unroll
            for (int i = 0; i < 4; ++i) {
                float4 a4 = *(const float4*)(As + (ty + 8 * i) * DIN + kc + k);
                float ak[4] = {a4.x, a4.y, a4.z, a4.w};
                #pragma unroll
                for (int s = 0; s < 4; ++s) {
                    float wj[4] = {w4[s].x, w4[s].y, w4[s].z, w4[s].w};
                    #pragma unroll
                    for (int j = 0; j < 4; ++j)
                        acc[i][j] = fmaf(ak[s], wj[j], acc[i][j]);
                }
            }
        }
    }

    // leaky_relu, store H, reduce row norms across the 32 tx lanes
    #pragma unroll
    for (int i = 0; i < 4; ++i) {
        float h[4];
        float s = 0.f;
        #pragma unroll
        for (int j = 0; j < 4; ++j) {
            float v = acc[i][j];
            h[j] = (v >= 0.f) ? v : LEAKY * v;
            s = fmaf(h[j], h[j], s);
        }
        float4 hv = {h[0], h[1], h[2], h[3]};
        const int r = row0 + ty + 8 * i;
        *(float4*)(H + (size_t)r * DOUT + 4 * tx) = hv;
        #pragma unroll
        for (int m = 16; m >= 1; m >>= 1)
            s += __shfl_xor(s, m, 64);
        if (tx == 0) norms[r] = sqrtf(s);
    }
}

// ---------------------------------------------------------------------------
// Kernel 2: out[b,i,j] = thresh(|dot(H_i,H_j) / max(n_i*n_j, eps)|)
// Symmetric: only upper-triangular 128x128 tile pairs (bi<=bj) are computed;
// off-diagonal tiles are written twice (direct + LDS-transposed mirror, both
// float4/64B-coalesced).
// 256 threads, 8x8 micro-tile: rows ty+16i, cols tx+16j (i,j=0..7).
// K staged in LDS in chunks of 32, rows padded 32->36 floats:
//   A-frag reads: 4 distinct addrs/instr (16-way broadcast, conflict-free)
//   B-frag reads: 2-way bank aliasing (free per m136)
// ---------------------------------------------------------------------------
#define TILE 128
#define NT   (NTOK / TILE)        // 32
#define NPAIR (NT * (NT + 1) / 2) // 528
#define KC   32
#define LDK  36                   // KC + 4 pad

__global__ __launch_bounds__(256, 3) void cos_kernel(
    const float* __restrict__ H, const float* __restrict__ norms,
    float* __restrict__ out)
{
    __shared__ float smem[2 * TILE * LDK];   // 36864 B; reused for transpose
    float* As = smem;
    float* Bs = smem + TILE * LDK;

    const int b = blockIdx.y;
    const int p = blockIdx.x;
    // decode pair index -> (bi <= bj), p = bj*(bj+1)/2 + bi
    int bj = (int)((sqrtf(8.f * (float)p + 1.f) - 1.f) * 0.5f);
    while ((bj + 1) * (bj + 2) / 2 <= p) ++bj;
    while (bj * (bj + 1) / 2 > p) --bj;
    const int bi = p - bj * (bj + 1) / 2;
    const int ti = bi * TILE;   // row tile origin
    const int tj = bj * TILE;   // col tile origin

    const int tid = threadIdx.x;
    const int tx = tid & 15;
    const int ty = tid >> 4;
    const float* Hb = H + (size_t)b * NTOK * DOUT;

    float acc[8][8];
    #pragma unroll
    for (int i = 0; i < 8; ++i)
        #pragma unroll
        for (int j = 0; j < 8; ++j) acc[i][j] = 0.f;

    for (int kc = 0; kc < DOUT; kc += KC) {
        __syncthreads();   // protect smem reuse across chunks
        // stage As,Bs: 128 rows x 32 floats each = 1024 float4; 4/thread/tile
        #pragma unroll
        for (int it = 0; it < 4; ++it) {
            int idx = tid + it * 256;      // 0..1023
            int r   = idx >> 3;            // 0..127
            int k4  = (idx & 7) << 2;      // 0,4,..,28
            *(float4*)(As + r * LDK + k4) =
                *(const float4*)(Hb + (size_t)(ti + r) * DOUT + kc + k4);
            *(float4*)(Bs + r * LDK + k4) =
                *(const float4*)(Hb + (size_t)(tj + r) * DOUT + kc + k4);
        }
        __syncthreads();

        #pragma unroll
        for (int k = 0; k < KC; k += 4) {
            float4 bf[8];
            #pragma unroll
            for (int j = 0; j < 8; ++j)
                bf[j] = *(const float4*)(Bs + (tx + 16 * j) * LDK + k);
            #pragma unroll
            for (int i = 0; i < 8; ++i) {
                float4 af = *(const float4*)(As + (ty + 16 * i) * LDK + k);
                #pragma unroll
                for (int j = 0; j < 8; ++j) {
                    acc[i][j] = fmaf(af.x, bf[j].x, acc[i][j]);
                    acc[i][j] = fmaf(af.y, bf[j].y, acc[i][j]);
                    acc[i][j] = fmaf(af.z, bf[j].z, acc[i][j]);
                    acc[i][j] = fmaf(af.w, bf[j].w, acc[i][j]);
                }
            }
        }
    }

    // Epilogue: cosine, abs, threshold (in-place into acc)
    float rn[8], cn[8];
    #pragma unroll
    for (int i = 0; i < 8; ++i) rn[i] = norms[b * NTOK + ti + ty + 16 * i];
    #pragma unroll
    for (int j = 0; j < 8; ++j) cn[j] = norms[b * NTOK + tj + tx + 16 * j];
    #pragma unroll
    for (int i = 0; i < 8; ++i)
        #pragma unroll
        for (int j = 0; j < 8; ++j) {
            float denom = fmaxf(rn[i] * cn[j], CEPS);
            float v = fabsf(acc[i][j] / denom);
            acc[i][j] = (v > THR) ? v : 0.f;
        }

    float* Ob = out + (size_t)b * NTOK * NTOK;

    // Direct write at (ti, tj): 16-float runs per row, 64B segments
    #pragma unroll
    for (int i = 0; i < 8; ++i) {
        const size_t rowbase = (size_t)(ti + ty + 16 * i) * NTOK + tj;
        #pragma unroll
        for (int j = 0; j < 8; ++j)
            Ob[rowbase + tx + 16 * j] = acc[i][j];
    }

    // Mirror write at (tj, ti) via LDS transpose, 2 half-passes of 64 cols
    if (bi != bj) {
        float* Tt = smem;   // viewed as [64][132]
        #pragma unroll
        for (int half = 0; half < 2; ++half) {
            __syncthreads();
            #pragma unroll
            for (int jj = 0; jj < 4; ++jj) {
                int j = 4 * half + jj;
                int c = tx + 16 * jj;      // local col within this half
                #pragma unroll
                for (int i = 0; i < 8; ++i)
                    Tt[c * 132 + ty + 16 * i] = acc[i][j];
            }
            __syncthreads();
            // write 64 rows x 128 cols = 2048 float4; 8 per thread
            #pragma unroll
            for (int it = 0; it < 8; ++it) {
                int idx = tid + it * 256;   // 0..2047
                int r   = idx >> 5;         // 0..63
                int c4  = (idx & 31) << 2;  // 0..124
                float4 val = *(const float4*)(Tt + r * 132 + c4);
                *(float4*)(Ob + (size_t)(tj + 64 * half + r) * NTOK + ti + c4) = val;
            }
        }
    }
}

extern "C" void kernel_launch(void* const* d_in, const int* in_sizes, int n_in,
                              void* d_out, int out_size, void* d_ws, size_t ws_size,
                              hipStream_t stream) {
    const float* A = (const float*)d_in[0];   // [4,4096,256]
    const float* W = (const float*)d_in[1];   // [256,128]
    float* out = (float*)d_out;               // [4,4096,4096]

    float* Hws   = (float*)d_ws;                   // 16384*128 floats = 8 MB
    float* norms = Hws + (size_t)RTOT * DOUT;      // 16384 floats

    proj_kernel<<<RTOT / 32, 256, 0, stream>>>(A, W, Hws, norms);
    cos_kernel<<<dim3(NPAIR, 4), 256, 0, stream>>>(Hws, norms, out);
}

// Round 3
// 400.812 us; speedup vs baseline: 1.3179x; 1.0494x over previous
//
#include <hip/hip_runtime.h>
#include <math.h>

// Problem constants: B=4, N=4096, D_in=256, D_out=128
#define NTOK 4096
#define RTOT 16384   // B*N
#define DIN  256
#define DOUT 128

constexpr float LEAKY = 0.01f;
constexpr float CEPS  = 0.001f;
constexpr float THR   = 0.1f;

// ---------------------------------------------------------------------------
// Kernel 1 (unchanged from R2): H = leaky_relu(A @ W); norms[r] = ||H[r,:]||
// ---------------------------------------------------------------------------
__global__ __launch_bounds__(256, 2) void proj_kernel(
    const float* __restrict__ A, const float* __restrict__ W,
    float* __restrict__ H, float* __restrict__ norms)
{
    __shared__ float As[32 * DIN];    // 32 KB
    __shared__ float Ws[64 * DOUT];   // 32 KB
    const int tid  = threadIdx.x;
    const int row0 = blockIdx.x * 32;

    {
        const float4* src = (const float4*)(A + (size_t)row0 * DIN);
        float4* dst = (float4*)As;
        #pragma unroll
        for (int it = 0; it < 8; ++it)
            dst[tid + it * 256] = src[tid + it * 256];
    }

    const int tx = tid & 31;
    const int ty = tid >> 5;

    float acc[4][4];
    #pragma unroll
    for (int i = 0; i < 4; ++i)
        #pragma unroll
        for (int j = 0; j < 4; ++j) acc[i][j] = 0.f;

    for (int kc = 0; kc < DIN; kc += 64) {
        __syncthreads();
        {
            const float4* wsrc = (const float4*)(W + (size_t)kc * DOUT);
            float4* wdst = (float4*)Ws;
            #pragma unroll
            for (int it = 0; it < 8; ++it)
                wdst[tid + it * 256] = wsrc[tid + it * 256];
        }
        __syncthreads();

        for (int k = 0; k < 64; k += 4) {
            float4 w4[4];
            #pragma unroll
            for (int s = 0; s < 4; ++s)
                w4[s] = *(const float4*)(Ws + (k + s) * DOUT + 4 * tx);
            #pragma unroll
            for (int i = 0; i < 4; ++i) {
                float4 a4 = *(const float4*)(As + (ty + 8 * i) * DIN + kc + k);
                float ak[4] = {a4.x, a4.y, a4.z, a4.w};
                #pragma unroll
                for (int s = 0; s < 4; ++s) {
                    float wj[4] = {w4[s].x, w4[s].y, w4[s].z, w4[s].w};
                    #pragma unroll
                    for (int j = 0; j < 4; ++j)
                        acc[i][j] = fmaf(ak[s], wj[j], acc[i][j]);
                }
            }
        }
    }

    #pragma unroll
    for (int i = 0; i < 4; ++i) {
        float h[4];
        float s = 0.f;
        #pragma unroll
        for (int j = 0; j < 4; ++j) {
            float v = acc[i][j];
            h[j] = (v >= 0.f) ? v : LEAKY * v;
            s = fmaf(h[j], h[j], s);
        }
        float4 hv = {h[0], h[1], h[2], h[3]};
        const int r = row0 + ty + 8 * i;
        *(float4*)(H + (size_t)r * DOUT + 4 * tx) = hv;
        #pragma unroll
        for (int m = 16; m >= 1; m >>= 1)
            s += __shfl_xor(s, m, 64);
        if (tx == 0) norms[r] = sqrtf(s);
    }
}

// ---------------------------------------------------------------------------
// Kernel 2: symmetric cosine tiles, 128x128 per block, upper-tri pairs only.
// 4 waves as 2x2 quadrants (qr,qc); each wave owns a 64x64 quadrant.
// Lane (tx=lane&7, ty=lane>>3): rows qr*64+ty+8i (i 0..7),
//                               cols qc*64+32jv+4tx (jv 0..1, float4 each).
// LDS: As row-major [128][36] (A-frag: banks 4ty+k, conflict-free broadcast),
//      Bs k-major  [32][132] (B-frag: banks 4(K+tx), all 32, conflict-free).
// All 16 K-loop LDS reads per k-step are 1-cycle 128B broadcasts.
// ---------------------------------------------------------------------------
#define TILE 128
#define NT   (NTOK / TILE)        // 32
#define NPAIR (NT * (NT + 1) / 2) // 528
#define KC   32
#define LDA  36                   // As pad
#define LDB  132                  // Bs k-major pad (16B-aligned rows)

__global__ __launch_bounds__(256, 4) void cos_kernel(
    const float* __restrict__ H, const float* __restrict__ norms,
    float* __restrict__ out)
{
    __shared__ float smem[TILE * LDA + KC * LDB];   // 18432+16896 B = 35328 B
    float* As = smem;                // [128][36] row-major
    float* Bs = smem + TILE * LDA;   // [32][132] k-major

    const int b = blockIdx.y;
    const int p = blockIdx.x;
    int bj = (int)((sqrtf(8.f * (float)p + 1.f) - 1.f) * 0.5f);
    while ((bj + 1) * (bj + 2) / 2 <= p) ++bj;
    while (bj * (bj + 1) / 2 > p) --bj;
    const int bi = p - bj * (bj + 1) / 2;
    const int ti = bi * TILE;
    const int tj = bj * TILE;

    const int tid  = threadIdx.x;
    const int wave = tid >> 6;
    const int lane = tid & 63;
    const int qr = wave & 1;          // row quadrant
    const int qc = wave >> 1;         // col quadrant
    const int tx = lane & 7;
    const int ty = lane >> 3;
    const float* Hb = H + (size_t)b * NTOK * DOUT;

    float4 acc4[8][2];
    #pragma unroll
    for (int i = 0; i < 8; ++i)
        #pragma unroll
        for (int jv = 0; jv < 2; ++jv)
            acc4[i][jv] = make_float4(0.f, 0.f, 0.f, 0.f);

    // staging indices (same for all chunks)
    const int sr = tid >> 3;          // 0..31 per it-step; combined below
    const int sk = (tid & 7) << 2;    // 0,4,..,28

    for (int kc = 0; kc < DOUT; kc += KC) {
        __syncthreads();
        // Stage As (row-major) and Bs (k-major, transpose-on-write).
        // 1024 float4 per tile, 4 per thread per tile.
        #pragma unroll
        for (int it = 0; it < 4; ++it) {
            const int r = sr + it * 32;   // 0..127
            // As
            *(float4*)(As + r * LDA + sk) =
                *(const float4*)(Hb + (size_t)(ti + r) * DOUT + kc + sk);
            // Bs: load float4 along k, scatter 4 scalars into k-major rows
            float4 v = *(const float4*)(Hb + (size_t)(tj + r) * DOUT + kc + sk);
            Bs[(sk + 0) * LDB + r] = v.x;
            Bs[(sk + 1) * LDB + r] = v.y;
            Bs[(sk + 2) * LDB + r] = v.z;
            Bs[(sk + 3) * LDB + r] = v.w;
        }
        __syncthreads();

        #pragma unroll
        for (int k = 0; k < KC; k += 4) {
            float4 af[8];
            #pragma unroll
            for (int i = 0; i < 8; ++i)
                af[i] = *(const float4*)(As + (qr * 64 + ty + 8 * i) * LDA + k);
            #pragma unroll
            for (int kk = 0; kk < 4; ++kk) {
                const float* brow = Bs + (k + kk) * LDB + qc * 64 + 4 * tx;
                float4 b0 = *(const float4*)(brow);
                float4 b1 = *(const float4*)(brow + 32);
                #pragma unroll
                for (int i = 0; i < 8; ++i) {
                    const float a = ((const float*)&af[i])[kk];
                    acc4[i][0].x = fmaf(a, b0.x, acc4[i][0].x);
                    acc4[i][0].y = fmaf(a, b0.y, acc4[i][0].y);
                    acc4[i][0].z = fmaf(a, b0.z, acc4[i][0].z);
                    acc4[i][0].w = fmaf(a, b0.w, acc4[i][0].w);
                    acc4[i][1].x = fmaf(a, b1.x, acc4[i][1].x);
                    acc4[i][1].y = fmaf(a, b1.y, acc4[i][1].y);
                    acc4[i][1].z = fmaf(a, b1.z, acc4[i][1].z);
                    acc4[i][1].w = fmaf(a, b1.w, acc4[i][1].w);
                }
            }
        }
    }

    // Epilogue: cosine, abs, threshold
    float rn[8];
    float4 cn[2];
    #pragma unroll
    for (int i = 0; i < 8; ++i)
        rn[i] = norms[b * NTOK + ti + qr * 64 + ty + 8 * i];
    #pragma unroll
    for (int jv = 0; jv < 2; ++jv) {
        const int c = tj + qc * 64 + 32 * jv + 4 * tx;
        cn[jv] = make_float4(norms[b * NTOK + c],     norms[b * NTOK + c + 1],
                             norms[b * NTOK + c + 2], norms[b * NTOK + c + 3]);
    }
    #pragma unroll
    for (int i = 0; i < 8; ++i)
        #pragma unroll
        for (int jv = 0; jv < 2; ++jv) {
            float* a = (float*)&acc4[i][jv];
            const float* n = (const float*)&cn[jv];
            #pragma unroll
            for (int s = 0; s < 4; ++s) {
                float denom = fmaxf(rn[i] * n[s], CEPS);
                float v = fabsf(a[s] / denom);
                a[s] = (v > THR) ? v : 0.f;
            }
        }

    float* Ob = out + (size_t)b * NTOK * NTOK;

    // Direct store: float4, lanes tx contiguous -> 128B runs
    #pragma unroll
    for (int i = 0; i < 8; ++i) {
        const size_t rowbase = (size_t)(ti + qr * 64 + ty + 8 * i) * NTOK + tj;
        #pragma unroll
        for (int jv = 0; jv < 2; ++jv)
            *(float4*)(Ob + rowbase + qc * 64 + 32 * jv + 4 * tx) = acc4[i][jv];
    }

    // Mirror store via LDS transpose (two halves of 64 original columns)
    if (bi != bj) {
        float* T = smem;   // [64][132], 33792 B <= smem
        #pragma unroll
        for (int h = 0; h < 2; ++h) {
            __syncthreads();
            if (qc == h) {
                #pragma unroll
                for (int jv = 0; jv < 2; ++jv) {
                    const int c0 = 32 * jv + 4 * tx;   // col within this half
                    #pragma unroll
                    for (int i = 0; i < 8; ++i) {
                        const int r = qr * 64 + ty + 8 * i;
                        const float* a = (const float*)&acc4[i][jv];
                        T[(c0 + 0) * LDB + r] = a[0];
                        T[(c0 + 1) * LDB + r] = a[1];
                        T[(c0 + 2) * LDB + r] = a[2];
                        T[(c0 + 3) * LDB + r] = a[3];
                    }
                }
            }
            __syncthreads();
            // 64 rows x 128 cols = 2048 float4, 8 per thread, coalesced
            #pragma unroll
            for (int it = 0; it < 8; ++it) {
                const int idx = tid + it * 256;
                const int rt  = idx >> 5;          // 0..63
                const int c4  = (idx & 31) << 2;   // 0..124
                *(float4*)(Ob + (size_t)(tj + 64 * h + rt) * NTOK + ti + c4) =
                    *(const float4*)(T + rt * LDB + c4);
            }
        }
    }
}

extern "C" void kernel_launch(void* const* d_in, const int* in_sizes, int n_in,
                              void* d_out, int out_size, void* d_ws, size_t ws_size,
                              hipStream_t stream) {
    const float* A = (const float*)d_in[0];   // [4,4096,256]
    const float* W = (const float*)d_in[1];   // [256,128]
    float* out = (float*)d_out;               // [4,4096,4096]

    float* Hws   = (float*)d_ws;                   // 16384*128 floats = 8 MB
    float* norms = Hws + (size_t)RTOT * DOUT;      // 16384 floats

    proj_kernel<<<RTOT / 32, 256, 0, stream>>>(A, W, Hws, norms);
    cos_kernel<<<dim3(NPAIR, 4), 256, 0, stream>>>(Hws, norms, out);
}